// Round 4
// baseline (64.216 us; speedup 1.0000x reference)
//
#include <hip/hip_runtime.h>
#include <cmath>

#define NB   8
#define NTT  1024
#define MM   64
#define LL   16
#define EE   128
#define NTB  8          // (b,nt) positions per block

typedef float f32x4 __attribute__((ext_vector_type(4)));
typedef float f32x2 __attribute__((ext_vector_type(2)));

__global__ __launch_bounds__(512, 8) void a2l_kernel(
    const float* __restrict__ agent,
    const float* __restrict__ lane,
    const float* __restrict__ W,
    const float* __restrict__ bias,
    float* __restrict__ out)
{
    __shared__ f32x4 sE0[NTB][MM];   // argmin point  (4 floats)
    __shared__ f32x4 sE1[NTB][MM];   // l = 0 slice
    __shared__ f32x4 sE2[NTB][MM];   // l = 15 slice

    const int tid       = threadIdx.x;
    const int bidx_base = blockIdx.x * NTB;          // 8-aligned => same b for all 8
    const int b         = bidx_base >> 10;

    // ---- Phase 1: 512 threads = 8 nt × 64 m, one edge each ----
    {
        const int nt = tid >> 6;          // 0..7
        const int m  = tid & 63;          // 0..63
        const int bidx = bidx_base + nt;

        const f32x4* ap = reinterpret_cast<const f32x4*>(agent + (size_t)bidx * 8);
        const f32x4 a0 = ap[0];
        const f32x4 a1 = ap[1];
        const float px = a0.x, py = a0.y, ps = a0.w, pc = a1.x;
        const bool z1 = (a0.x == 0.f) & (a0.y == 0.f) & (a0.z == 0.f) & (a0.w == 0.f) &
                        (a1.x == 0.f) & (a1.y == 0.f) & (a1.z == 0.f) & (a1.w == 0.f);
        const float f1 = z1 ? 0.f : 1.f;

        const f32x4* lp = reinterpret_cast<const f32x4*>(lane + ((size_t)b * MM + m) * 64);

        float best = INFINITY;
        f32x4 eMin = (f32x4)(0.f);
        f32x4 eL0  = (f32x4)(0.f);
        f32x4 eL15 = (f32x4)(0.f);
#pragma unroll
        for (int l = 0; l < LL; ++l) {
            const f32x4 lv = lp[l];                   // lx, ly, ls, lc
            const bool z2 = (lv.x == 0.f) & (lv.y == 0.f) & (lv.z == 0.f) & (lv.w == 0.f);
            const float f = z2 ? 0.f : f1;
            const float dxw = px - lv.x;
            const float dyw = py - lv.y;
            f32x4 v;
            v.x = (dxw * lv.w + dyw * lv.z) * 0.1f * f;   // delta_x / 10
            v.y = (dyw * lv.w - dxw * lv.z) * 0.1f * f;   // delta_y / 10
            v.z = (ps * lv.w - pc * lv.z) * f;            // ds
            v.w = (pc * lv.w + ps * lv.z) * f;            // dc
            const float ad = fabsf(v.x);
            if (ad < best) { best = ad; eMin = v; }       // strict < keeps FIRST min
            if (l == 0)      eL0  = v;
            if (l == LL - 1) eL15 = v;
        }
        sE0[nt][m] = eMin;
        sE1[nt][m] = eL0;
        sE2[nt][m] = eL15;
    }
    __syncthreads();

    // ---- Phase 2: thread owns 2 consecutive channels; 8 nt × 8 m-groups ----
    const int ch = (tid & 63) * 2;      // channel base 0..126 (full-wave span)
    const int mg = tid >> 6;            // 0..7, uniform per wave

    float w[2][12];
#pragma unroll
    for (int j = 0; j < 2; ++j) {
        const f32x4* wp = reinterpret_cast<const f32x4*>(W + (size_t)(ch + j) * 12);
        const f32x4 w0 = wp[0], w1 = wp[1], w2 = wp[2];
        w[j][0] = w0.x; w[j][1]  = w0.y; w[j][2]  = w0.z; w[j][3]  = w0.w;
        w[j][4] = w1.x; w[j][5]  = w1.y; w[j][6]  = w1.z; w[j][7]  = w1.w;
        w[j][8] = w2.x; w[j][9]  = w2.y; w[j][10] = w2.z; w[j][11] = w2.w;
    }
    const float bb0 = bias[ch + 0];
    const float bb1 = bias[ch + 1];

    for (int nt = 0; nt < NTB; ++nt) {
        float* outp = out + (size_t)(bidx_base + nt) * (MM * EE);
#pragma unroll
        for (int it = 0; it < 8; ++it) {
            const int m = it * 8 + mg;
            const f32x4 p = sE0[nt][m];    // full-wave broadcast, conflict-free
            const f32x4 q = sE1[nt][m];
            const f32x4 r = sE2[nt][m];
            float acc0 = bb0, acc1 = bb1;
            acc0 += p.x*w[0][0] + p.y*w[0][1] + p.z*w[0][2]  + p.w*w[0][3]
                  + q.x*w[0][4] + q.y*w[0][5] + q.z*w[0][6]  + q.w*w[0][7]
                  + r.x*w[0][8] + r.y*w[0][9] + r.z*w[0][10] + r.w*w[0][11];
            acc1 += p.x*w[1][0] + p.y*w[1][1] + p.z*w[1][2]  + p.w*w[1][3]
                  + q.x*w[1][4] + q.y*w[1][5] + q.z*w[1][6]  + q.w*w[1][7]
                  + r.x*w[1][8] + r.y*w[1][9] + r.z*w[1][10] + r.w*w[1][11];
            f32x2 res;
            res.x = acc0; res.y = acc1;
            *reinterpret_cast<f32x2*>(outp + (size_t)m * EE + ch) = res;
        }
    }
}

extern "C" void kernel_launch(void* const* d_in, const int* in_sizes, int n_in,
                              void* d_out, int out_size, void* d_ws, size_t ws_size,
                              hipStream_t stream) {
    const float* agent = (const float*)d_in[0];
    const float* lane  = (const float*)d_in[1];
    const float* W     = (const float*)d_in[2];
    const float* bias  = (const float*)d_in[3];
    float* out = (float*)d_out;

    dim3 grid((NB * NTT) / NTB);   // 1024 blocks, 4 per CU, fully resident
    dim3 block(512);
    a2l_kernel<<<grid, block, 0, stream>>>(agent, lane, W, bias, out);
}